// Round 13
// baseline (1612.416 us; speedup 1.0000x reference)
//
#include <hip/hip_runtime.h>
#include <hip/hip_fp16.h>
#include <math.h>

#define BB 512
#define TT 256
#define DD 128
#define HH 256
#define OO 128
#define KH 640   // 3*D + H
#define BT (BB*TT)

typedef unsigned int uint_t;
typedef _Float16 f16x8 __attribute__((ext_vector_type(8)));
typedef float f32x4 __attribute__((ext_vector_type(4)));

__device__ __forceinline__ float sigmoidf_(float x){ return 1.0f/(1.0f+__expf(-x)); }
__device__ __forceinline__ float tanhf_(float x){ float e = __expf(-2.0f*x); return 2.0f/(1.0f+e) - 1.0f; }
__device__ __forceinline__ float clipd_(float x){ return fminf(fmaxf(x, 0.f), 100.f); }

typedef _Float16 h2v __attribute__((ext_vector_type(2)));
__device__ __forceinline__ float d2(uint_t a, uint_t b, float c){
#if __has_builtin(__builtin_amdgcn_fdot2)
    return __builtin_amdgcn_fdot2(__builtin_bit_cast(h2v, a), __builtin_bit_cast(h2v, b), c, false);
#else
    __half2 ha = __builtin_bit_cast(__half2, a);
    __half2 hb = __builtin_bit_cast(__half2, b);
    return c + __half2float(ha.x)*__half2float(hb.x) + __half2float(ha.y)*__half2float(hb.y);
#endif
}
__device__ __forceinline__ uint_t pack2(float a, float b){
    __half2 h; h.x = __float2half(a); h.y = __float2half(b);
    return __builtin_bit_cast(uint_t, h);
}

// ---- ws layout ----
static const size_t SZ_XC   = (size_t)BT*384*2;
static const size_t SZ_PX64 = (size_t)64*786432;    // one Tc=64 px buffer
static const size_t TAIL_SZ = 589824 + 393216 + 3072 + 262144 + 524288 + 32768*3 + 65536;

// ---- weight prep ----
__global__ __launch_bounds__(128) void k_wprep(const float* __restrict__ Wz, const float* __restrict__ Wr,
                                               const float* __restrict__ Wh, const float* __restrict__ bz,
                                               const float* __restrict__ br, const float* __restrict__ bh,
                                               __half* __restrict__ Wcat, __half* __restrict__ Wrec,
                                               float* __restrict__ bcat){
    int gj = blockIdx.x; int j = gj & 255;
    const float* src  = (gj < 256 ? Wz : (gj < 512 ? Wr : Wh)) + (size_t)j*KH;
    const float* bsrc = (gj < 256 ? bz : (gj < 512 ? br : bh));
    for(int k=threadIdx.x; k<384; k+=128) Wcat[(size_t)gj*384 + k] = __float2half(src[k]);
    for(int k=threadIdx.x; k<256; k+=128) Wrec[(size_t)gj*256 + k] = __float2half(src[384+k]);
    if(threadIdx.x==0) bcat[gj] = bsrc[j];
}

__global__ __launch_bounds__(256) void k_cvt(const float* __restrict__ a, const float* __restrict__ b,
                                             const float* __restrict__ c, const float* __restrict__ d,
                                             __half* __restrict__ oa, __half* __restrict__ ob,
                                             __half* __restrict__ oc, __half* __restrict__ od){
    int i = blockIdx.x*256 + threadIdx.x;
    if(i < 16384){
        oa[i] = __float2half(a[i]);
        ob[i] = __float2half(b[i]);
        oc[i] = __float2half(c[i]);
    }
    od[i] = __float2half(d[i]);
}

// ---- xmean via linearity ----
__global__ __launch_bounds__(256) void k_meanx(const float* __restrict__ x,
                                               const float* __restrict__ Wemb,
                                               const float* __restrict__ bemb,
                                               float* __restrict__ xmean){
    __shared__ float red[2][128];
    __shared__ __align__(16) float xr[128];
    const int tid = threadIdx.x;
    const int b = blockIdx.x;
    const int col = tid & 127, hf = tid >> 7;
    float s = 0.f;
    const float* px = x + ((size_t)b*TT + hf*128)*DD + col;
    for(int t=0;t<128;++t) s += px[(size_t)t*DD];
    red[hf][col] = s;
    __syncthreads();
    if(tid < 128) xr[tid] = (red[0][tid] + red[1][tid]) * (1.0f/TT);
    __syncthreads();
    if(tid < 128){
        float acc = bemb[tid];
        const float4* wr = (const float4*)(Wemb + tid*DD);
        const float4* xv = (const float4*)xr;
        for(int k4=0;k4<32;++k4){
            float4 w = wr[k4], v = xv[k4];
            acc += w.x*v.x + w.y*v.y + w.z*v.z + w.w*v.w;
        }
        xmean[b*DD + tid] = acc;
    }
}

// ---- fused emb + gate chain (MFMA) ----
__global__ __launch_bounds__(256,2) void k_embgate(const float* __restrict__ x,
    const float* __restrict__ xmask, const float* __restrict__ xdelta,
    const float* __restrict__ noise,
    const __half* __restrict__ Wembh, const float* __restrict__ bemb,
    const __half* __restrict__ Wd1h, const float* __restrict__ bd1,
    const __half* __restrict__ Wd2h, const float* __restrict__ bd2,
    const __half* __restrict__ Wch,  const float* __restrict__ bc,
    const float* __restrict__ xmean, __half* __restrict__ xc){
    __shared__ __align__(16) uint4 TaU[128*16];
    __shared__ __align__(16) uint4 TdU[128*16];
    __half* TaH = (__half*)TaU;
    const int tid = threadIdx.x;
    const long row0 = (long)blockIdx.x*128;
    const int b = (int)(row0 >> 8);

    {
        const int srow = tid>>1, shalf = tid&1;
        const long gr = row0 + srow;
        const float4* gx = (const float4*)(x      + gr*DD + shalf*64);
        const float4* gd = (const float4*)(xdelta + gr*DD + shalf*64);
        const float4* gm = (const float4*)(xmask  + gr*DD + shalf*64);
        uint4* xcu = (uint4*)(xc + gr*384);
        #pragma unroll
        for(int u=0;u<8;++u){
            float4 a = gx[u*2], q = gx[u*2+1];
            uint4 pk;
            pk.x = pack2(a.x,a.y); pk.y = pack2(a.z,a.w);
            pk.z = pack2(q.x,q.y); pk.w = pack2(q.z,q.w);
            int unit = shalf*8 + u;
            TaU[srow*16 + (unit ^ (srow&7))] = pk;
        }
        #pragma unroll
        for(int u=0;u<8;++u){
            float4 a = gd[u*2], q = gd[u*2+1];
            uint4 pk;
            pk.x = pack2(clipd_(a.x), clipd_(a.y));
            pk.y = pack2(clipd_(a.z), clipd_(a.w));
            pk.z = pack2(clipd_(q.x), clipd_(q.y));
            pk.w = pack2(clipd_(q.z), clipd_(q.w));
            int unit = shalf*8 + u;
            TdU[srow*16 + (unit ^ (srow&7))] = pk;
            xcu[32 + unit] = pk;
        }
        #pragma unroll
        for(int u=0;u<8;++u){
            float4 a = gm[u*2], q = gm[u*2+1];
            uint4 pk;
            pk.x = pack2(a.x,a.y); pk.y = pack2(a.z,a.w);
            pk.z = pack2(q.x,q.y); pk.w = pack2(q.z,q.w);
            xcu[16 + shalf*8 + u] = pk;
        }
    }
    __syncthreads();

    const int wv = tid>>6, lane = tid&63, g = lane>>4, r16 = lane&15;
    const int wrow0 = wv*32;
    const uint4* WeU = (const uint4*)Wembh;
    const uint4* W1U = (const uint4*)Wd1h;
    const uint4* W2U = (const uint4*)Wd2h;
    const uint4* WcU = (const uint4*)Wch;
    f32x4 acc[2][8];

    // stage 1: x1 -> registers
    f32x4 x1f[2][8];
    #pragma unroll
    for(int i=0;i<2;++i)
        #pragma unroll
        for(int jj=0;jj<8;++jj) x1f[i][jj] = (f32x4){0.f,0.f,0.f,0.f};
    #pragma unroll
    for(int ks=0;ks<4;++ks){
        f16x8 af[2], bf[8];
        #pragma unroll
        for(int mf=0;mf<2;++mf){
            int rr = wrow0 + mf*16 + r16;
            af[mf] = __builtin_bit_cast(f16x8, TaU[rr*16 + ((ks*4+g) ^ (rr&7))]);
        }
        #pragma unroll
        for(int nf=0;nf<8;++nf){
            int col = nf*16 + r16;
            bf[nf] = __builtin_bit_cast(f16x8, WeU[col*16 + ks*4 + g]);
        }
        #pragma unroll
        for(int mf=0;mf<2;++mf)
            #pragma unroll
            for(int nf=0;nf<8;++nf)
                x1f[mf][nf] = __builtin_amdgcn_mfma_f32_16x16x32_f16(af[mf], bf[nf], x1f[mf][nf], 0,0,0);
    }
    #pragma unroll
    for(int nf=0;nf<8;++nf){
        float bb = bemb[nf*16 + r16];
        #pragma unroll
        for(int mf=0;mf<2;++mf)
            #pragma unroll
            for(int e=0;e<4;++e) x1f[mf][nf][e] += bb;
    }

    // stage 2: t1 = relu(d @ Wd1^T + b1) -> TaU
    #pragma unroll
    for(int i=0;i<2;++i)
        #pragma unroll
        for(int jj=0;jj<8;++jj) acc[i][jj] = (f32x4){0.f,0.f,0.f,0.f};
    #pragma unroll
    for(int ks=0;ks<4;++ks){
        f16x8 af[2], bf[8];
        #pragma unroll
        for(int mf=0;mf<2;++mf){
            int rr = wrow0 + mf*16 + r16;
            af[mf] = __builtin_bit_cast(f16x8, TdU[rr*16 + ((ks*4+g) ^ (rr&7))]);
        }
        #pragma unroll
        for(int nf=0;nf<8;++nf){
            int col = nf*16 + r16;
            bf[nf] = __builtin_bit_cast(f16x8, W1U[col*16 + ks*4 + g]);
        }
        #pragma unroll
        for(int mf=0;mf<2;++mf)
            #pragma unroll
            for(int nf=0;nf<8;++nf)
                acc[mf][nf] = __builtin_amdgcn_mfma_f32_16x16x32_f16(af[mf], bf[nf], acc[mf][nf], 0,0,0);
    }
    #pragma unroll
    for(int nf=0;nf<8;++nf){
        int col = nf*16 + r16;
        float bb = bd1[col];
        int u = col>>3, cl = col&7;
        #pragma unroll
        for(int mf=0;mf<2;++mf){
            int rowb = wrow0 + mf*16 + g*4;
            f32x4 v = acc[mf][nf];
            #pragma unroll
            for(int e=0;e<4;++e){
                int rr = rowb + e;
                float tt = v[e] + bb; tt = tt > 0.f ? tt : 0.f;
                TaH[(rr*16 + (u ^ (rr&7)))*8 + cl] = __float2half(tt);
            }
        }
    }

    // stage 3: gamma
    #pragma unroll
    for(int i=0;i<2;++i)
        #pragma unroll
        for(int jj=0;jj<8;++jj) acc[i][jj] = (f32x4){0.f,0.f,0.f,0.f};
    #pragma unroll
    for(int ks=0;ks<4;++ks){
        f16x8 af[2], bf[8];
        #pragma unroll
        for(int mf=0;mf<2;++mf){
            int rr = wrow0 + mf*16 + r16;
            af[mf] = __builtin_bit_cast(f16x8, TaU[rr*16 + ((ks*4+g) ^ (rr&7))]);
        }
        #pragma unroll
        for(int nf=0;nf<8;++nf){
            int col = nf*16 + r16;
            bf[nf] = __builtin_bit_cast(f16x8, W2U[col*16 + ks*4 + g]);
        }
        #pragma unroll
        for(int mf=0;mf<2;++mf)
            #pragma unroll
            for(int nf=0;nf<8;++nf)
                acc[mf][nf] = __builtin_amdgcn_mfma_f32_16x16x32_f16(af[mf], bf[nf], acc[mf][nf], 0,0,0);
    }

    // stage 4: x_hat -> TaU
    #pragma unroll
    for(int nf=0;nf<8;++nf){
        int col = nf*16 + r16;
        float b2 = bd2[col];
        float xm = xmean[b*DD + col];
        int u = col>>3, cl = col&7;
        #pragma unroll
        for(int mf=0;mf<2;++mf){
            int rowb = wrow0 + mf*16 + g*4;
            f32x4 v = acc[mf][nf];
            #pragma unroll
            for(int e=0;e<4;++e){
                int rr = rowb + e;
                long grow = row0 + rr;
                float m  = xmask[grow*DD + col];
                float gmm = sigmoidf_(v[e] + b2);
                float xh = m*x1f[mf][nf][e] + (1.f-m)*gmm*xm;
                TaH[(rr*16 + (u ^ (rr&7)))*8 + cl] = __float2half(xh);
            }
        }
    }

    // stage 5: conf
    #pragma unroll
    for(int i=0;i<2;++i)
        #pragma unroll
        for(int jj=0;jj<8;++jj) acc[i][jj] = (f32x4){0.f,0.f,0.f,0.f};
    #pragma unroll
    for(int ks=0;ks<4;++ks){
        f16x8 af[2], bf[8];
        #pragma unroll
        for(int mf=0;mf<2;++mf){
            int rr = wrow0 + mf*16 + r16;
            af[mf] = __builtin_bit_cast(f16x8, TaU[rr*16 + ((ks*4+g) ^ (rr&7))]);
        }
        #pragma unroll
        for(int nf=0;nf<8;++nf){
            int col = nf*16 + r16;
            bf[nf] = __builtin_bit_cast(f16x8, WcU[col*32 + ks*4 + g]);
        }
        #pragma unroll
        for(int mf=0;mf<2;++mf)
            #pragma unroll
            for(int nf=0;nf<8;++nf)
                acc[mf][nf] = __builtin_amdgcn_mfma_f32_16x16x32_f16(af[mf], bf[nf], acc[mf][nf], 0,0,0);
    }
    #pragma unroll
    for(int ks=0;ks<4;++ks){
        f16x8 af[2], bf[8];
        #pragma unroll
        for(int mf=0;mf<2;++mf){
            int rr = wrow0 + mf*16 + r16;
            af[mf] = __builtin_bit_cast(f16x8, TdU[rr*16 + ((ks*4+g) ^ (rr&7))]);
        }
        #pragma unroll
        for(int nf=0;nf<8;++nf){
            int col = nf*16 + r16;
            bf[nf] = __builtin_bit_cast(f16x8, WcU[col*32 + 16 + ks*4 + g]);
        }
        #pragma unroll
        for(int mf=0;mf<2;++mf)
            #pragma unroll
            for(int nf=0;nf<8;++nf)
                acc[mf][nf] = __builtin_amdgcn_mfma_f32_16x16x32_f16(af[mf], bf[nf], acc[mf][nf], 0,0,0);
    }

    // stage 6: x_final
    #pragma unroll
    for(int nf=0;nf<8;++nf){
        int col = nf*16 + r16;
        float bcc = bc[col];
        int u = col>>3, cl = col&7;
        #pragma unroll
        for(int mf=0;mf<2;++mf){
            int rowb = wrow0 + mf*16 + g*4;
            f32x4 v = acc[mf][nf];
            #pragma unroll
            for(int e=0;e<4;++e){
                int rr = rowb + e;
                long grow = row0 + rr;
                float conf = sigmoidf_(v[e] + bcc);
                float xh = __half2float(TaH[(rr*16 + (u ^ (rr&7)))*8 + cl]);
                float nz = noise[grow*DD + col];
                xc[grow*384 + col] = __float2half(xh*conf + nz*(1.f-conf));
            }
        }
    }
}

// ---- MFMA projection (standalone, chunk c0) ----
__global__ __launch_bounds__(256) void k_projm(const __half* __restrict__ xc,
                                               const __half* __restrict__ Wcat,
                                               const float* __restrict__ bcat,
                                               __half* __restrict__ px,
                                               int lTc, int chunk){
    __shared__ __align__(16) __half As[128*64];
    __shared__ __align__(16) __half Bs[128*64];
    const int tid = threadIdx.x;
    const int rblk = blockIdx.x * 128;
    const int ct0  = blockIdx.y * 128;
    const int mTc = (1<<lTc) - 1;

    const int row = tid >> 1;
    const int hf  = tid & 1;
    const int ar  = rblk + row;
    const long grow = ((long)(ar >> lTc))*TT + ((long)chunk << lTc) + (ar & mTc);
    const uint4* gA = (const uint4*)(xc + grow*384);
    const uint4* gB = (const uint4*)(Wcat + (size_t)(ct0 + row)*384);
    uint4* AsU = (uint4*)As;
    uint4* BsU = (uint4*)Bs;

    const int wv = tid >> 6;
    const int wm = wv >> 1, wn = wv & 1;
    const int l  = tid & 63;
    const int g  = l >> 4, r16 = l & 15;

    f32x4 acc[4][4];
    #pragma unroll
    for(int i=0;i<4;++i)
        #pragma unroll
        for(int jj=0;jj<4;++jj) acc[i][jj] = (f32x4){0.f,0.f,0.f,0.f};

    for(int bk=0; bk<6; ++bk){
        uint4 av[4], bv[4];
        #pragma unroll
        for(int u=0;u<4;++u){ av[u] = gA[bk*8 + hf*4 + u]; bv[u] = gB[bk*8 + hf*4 + u]; }
        if(bk) __syncthreads();
        #pragma unroll
        for(int u=0;u<4;++u){
            int uu = hf*4 + u;
            AsU[row*8 + (uu ^ (row&7))] = av[u];
            BsU[row*8 + (uu ^ (row&7))] = bv[u];
        }
        __syncthreads();
        #pragma unroll
        for(int ks=0;ks<2;++ks){
            f16x8 af[4], bf[4];
            #pragma unroll
            for(int mf=0;mf<4;++mf){
                int rr = wm*64 + mf*16 + r16;
                af[mf] = __builtin_bit_cast(f16x8, AsU[rr*8 + ((ks*4+g) ^ (rr&7))]);
            }
            #pragma unroll
            for(int nf=0;nf<4;++nf){
                int rr = wn*64 + nf*16 + r16;
                bf[nf] = __builtin_bit_cast(f16x8, BsU[rr*8 + ((ks*4+g) ^ (rr&7))]);
            }
            #pragma unroll
            for(int mf=0;mf<4;++mf)
                #pragma unroll
                for(int nf=0;nf<4;++nf)
                    acc[mf][nf] = __builtin_amdgcn_mfma_f32_16x16x32_f16(af[mf], bf[nf], acc[mf][nf], 0,0,0);
        }
    }
    #pragma unroll
    for(int nf=0; nf<4; ++nf){
        int col = ct0 + wn*64 + nf*16 + r16;
        float bb = bcat[col];
        #pragma unroll
        for(int mf=0; mf<4; ++mf){
            int r0 = rblk + wm*64 + mf*16 + g*4;
            f32x4 v = acc[mf][nf];
            #pragma unroll
            for(int e=0;e<4;++e)
                px[(size_t)(r0+e)*768 + col] = __float2half(v[e] + bb);
        }
    }
}

// ---- chunked GRU (round-6 proven) ----
__global__ __launch_bounds__(512,2) void k_gruc(const __half* __restrict__ pxc,
                                                const __half* __restrict__ Wrec,
                                                float* __restrict__ hstate,
                                                int Tc, int init){
    __shared__ __align__(16) uint_t hU[2][136];
    __shared__ __align__(16) uint_t rhU[2][136];
    __shared__ __align__(16) uint_t pxs[2][768];
    const int t  = threadIdx.x;
    const int j  = t >> 1;
    const int kh = t & 1;
    const long b0 = (long)blockIdx.x*2;
    const uint_t* Wr32 = (const uint_t*)Wrec;

    uint_t wz[64], wr[64], wh[64];
    #pragma unroll
    for(int q=0;q<64;++q){
        wz[q] = Wr32[(size_t)(      j)*128 + kh*64 + q];
        wr[q] = Wr32[(size_t)(256 + j)*128 + kh*64 + q];
        wh[q] = Wr32[(size_t)(512 + j)*128 + kh*64 + q];
    }

    const uint_t* px32 = (const uint_t*)pxc;
    auto ldpx = [&](int tl, int f)->uint_t{
        int row = (f >= 384); int off = f - row*384;
        return px32[((size_t)(b0+row)*Tc + tl)*384 + off];
    };
    const int hidx = ((j>>7)*136) + (j&127);

    float hreg0, hreg1;
    if(init){ hreg0 = 0.f; hreg1 = 0.f; }
    else    { hreg0 = hstate[(b0+0)*HH + j]; hreg1 = hstate[(b0+1)*HH + j]; }
    if(kh==0){
        ((__half*)hU[0])[hidx] = __float2half(hreg0);
        ((__half*)hU[1])[hidx] = __float2half(hreg1);
    }
    pxs[0][t] = ldpx(0, t);
    if(t < 256) pxs[0][t+512] = ldpx(0, t+512);
    __syncthreads();

    const uint_t* h0p = hU[0]  + kh*68;
    const uint_t* h1p = hU[1]  + kh*68;
    const uint_t* r0p = rhU[0] + kh*68;
    const uint_t* r1p = rhU[1] + kh*68;

    for(int s=0; s<Tc; ++s){
        const int cur = s & 1;
        uint_t nf0 = 0, nf1 = 0;
        if(s < Tc-1){ nf0 = ldpx(s+1, t); if(t < 256) nf1 = ldpx(s+1, t+512); }

        const __half* pxcur = (const __half*)pxs[cur];
        float az0=0.f, az1=0.f, ar0=0.f, ar1=0.f;
        #pragma unroll
        for(int q=0;q<64;q+=4){
            uint4 hv0 = *(const uint4*)(h0p + q);
            uint4 hv1 = *(const uint4*)(h1p + q);
            az0=d2(wz[q+0],hv0.x,az0); ar0=d2(wr[q+0],hv0.x,ar0); az1=d2(wz[q+0],hv1.x,az1); ar1=d2(wr[q+0],hv1.x,ar1);
            az0=d2(wz[q+1],hv0.y,az0); ar0=d2(wr[q+1],hv0.y,ar0); az1=d2(wz[q+1],hv1.y,az1); ar1=d2(wr[q+1],hv1.y,ar1);
            az0=d2(wz[q+2],hv0.z,az0); ar0=d2(wr[q+2],hv0.z,ar0); az1=d2(wz[q+2],hv1.z,az1); ar1=d2(wr[q+2],hv1.z,ar1);
            az0=d2(wz[q+3],hv0.w,az0); ar0=d2(wr[q+3],hv0.w,ar0); az1=d2(wz[q+3],hv1.w,az1); ar1=d2(wr[q+3],hv1.w,ar1);
        }
        az0 += __shfl_xor(az0,1); az1 += __shfl_xor(az1,1);
        ar0 += __shfl_xor(ar0,1); ar1 += __shfl_xor(ar1,1);
        float z0 = sigmoidf_(__half2float(pxcur[        j]) + az0);
        float z1 = sigmoidf_(__half2float(pxcur[768   + j]) + az1);
        float r0 = sigmoidf_(__half2float(pxcur[256   + j]) + ar0);
        float r1 = sigmoidf_(__half2float(pxcur[768+256+j]) + ar1);
        if(kh==0){
            ((__half*)rhU[0])[hidx] = __float2half(r0*hreg0);
            ((__half*)rhU[1])[hidx] = __float2half(r1*hreg1);
        }
        __syncthreads();
        float ah0=0.f, ah1=0.f;
        #pragma unroll
        for(int q=0;q<64;q+=4){
            uint4 rv0 = *(const uint4*)(r0p + q);
            uint4 rv1 = *(const uint4*)(r1p + q);
            ah0=d2(wh[q+0],rv0.x,ah0); ah1=d2(wh[q+0],rv1.x,ah1);
            ah0=d2(wh[q+1],rv0.y,ah0); ah1=d2(wh[q+1],rv1.y,ah1);
            ah0=d2(wh[q+2],rv0.z,ah0); ah1=d2(wh[q+2],rv1.z,ah1);
            ah0=d2(wh[q+3],rv0.w,ah0); ah1=d2(wh[q+3],rv1.w,ah1);
        }
        ah0 += __shfl_xor(ah0,1); ah1 += __shfl_xor(ah1,1);
        float ht0 = tanhf_(__half2float(pxcur[512    + j]) + ah0);
        float ht1 = tanhf_(__half2float(pxcur[768+512+j]) + ah1);
        hreg0 = (1.f - z0)*hreg0 + z0*ht0;
        hreg1 = (1.f - z1)*hreg1 + z1*ht1;
        if(kh==0){
            ((__half*)hU[0])[hidx] = __float2half(hreg0);
            ((__half*)hU[1])[hidx] = __float2half(hreg1);
        }
        if(s < Tc-1){
            pxs[cur^1][t] = nf0;
            if(t < 256) pxs[cur^1][t+512] = nf1;
        }
        __syncthreads();
    }
    if(kh==0){
        hstate[(b0+0)*HH + j] = hreg0;
        hstate[(b0+1)*HH + j] = hreg1;
    }
}

// ---- FUSED: blocks [0,256) = gruc(Tc=64, pxR); blocks [256,1792) = projm -> pxW ----
// projm side runs with 512 threads: etid=tid&255 duplicates lower half's loads
// (broadcast, benign); all __syncthreads unconditional; stores guarded tid<256.
__global__ __launch_bounds__(512,2) void k_fused(const __half* __restrict__ pxR,
                                                 __half* __restrict__ pxW,
                                                 const __half* __restrict__ xc,
                                                 const __half* __restrict__ Wcat,
                                                 const float* __restrict__ bcat,
                                                 const __half* __restrict__ Wrec,
                                                 float* __restrict__ hstate,
                                                 int init, int chunkW){
    __shared__ __align__(16) char smem[32768];
    const int tid = threadIdx.x;

    if(blockIdx.x < 256){
        // ================= gruc body, Tc=64 =================
        uint_t* hUb  = (uint_t*)smem;        // [2][136]
        uint_t* rhUb = hUb + 272;            // [2][136]
        uint_t* pxsb = rhUb + 272;           // [2][768]
        const int t  = tid;
        const int j  = t >> 1;
        const int kh = t & 1;
        const long b0 = (long)blockIdx.x*2;
        const uint_t* Wr32 = (const uint_t*)Wrec;

        uint_t wz[64], wr[64], wh[64];
        #pragma unroll
        for(int q=0;q<64;++q){
            wz[q] = Wr32[(size_t)(      j)*128 + kh*64 + q];
            wr[q] = Wr32[(size_t)(256 + j)*128 + kh*64 + q];
            wh[q] = Wr32[(size_t)(512 + j)*128 + kh*64 + q];
        }
        const uint_t* px32 = (const uint_t*)pxR;
        auto ldpx = [&](int tl, int f)->uint_t{
            int row = (f >= 384); int off = f - row*384;
            return px32[((size_t)(b0+row)*64 + tl)*384 + off];
        };
        const int hidx = ((j>>7)*136) + (j&127);

        float hreg0, hreg1;
        if(init){ hreg0 = 0.f; hreg1 = 0.f; }
        else    { hreg0 = hstate[(b0+0)*HH + j]; hreg1 = hstate[(b0+1)*HH + j]; }
        if(kh==0){
            ((__half*)(hUb      ))[hidx] = __float2half(hreg0);
            ((__half*)(hUb + 136))[hidx] = __float2half(hreg1);
        }
        pxsb[t] = ldpx(0, t);
        if(t < 256) pxsb[t+512] = ldpx(0, t+512);
        __syncthreads();

        const uint_t* h0p = hUb        + kh*68;
        const uint_t* h1p = hUb + 136  + kh*68;
        const uint_t* r0p = rhUb       + kh*68;
        const uint_t* r1p = rhUb + 136 + kh*68;

        for(int s=0; s<64; ++s){
            const int cur = s & 1;
            uint_t nf0 = 0, nf1 = 0;
            if(s < 63){ nf0 = ldpx(s+1, t); if(t < 256) nf1 = ldpx(s+1, t+512); }

            const __half* pxcur = (const __half*)(pxsb + cur*768);
            float az0=0.f, az1=0.f, ar0=0.f, ar1=0.f;
            #pragma unroll
            for(int q=0;q<64;q+=4){
                uint4 hv0 = *(const uint4*)(h0p + q);
                uint4 hv1 = *(const uint4*)(h1p + q);
                az0=d2(wz[q+0],hv0.x,az0); ar0=d2(wr[q+0],hv0.x,ar0); az1=d2(wz[q+0],hv1.x,az1); ar1=d2(wr[q+0],hv1.x,ar1);
                az0=d2(wz[q+1],hv0.y,az0); ar0=d2(wr[q+1],hv0.y,ar0); az1=d2(wz[q+1],hv1.y,az1); ar1=d2(wr[q+1],hv1.y,ar1);
                az0=d2(wz[q+2],hv0.z,az0); ar0=d2(wr[q+2],hv0.z,ar0); az1=d2(wz[q+2],hv1.z,az1); ar1=d2(wr[q+2],hv1.z,ar1);
                az0=d2(wz[q+3],hv0.w,az0); ar0=d2(wr[q+3],hv0.w,ar0); az1=d2(wz[q+3],hv1.w,az1); ar1=d2(wr[q+3],hv1.w,ar1);
            }
            az0 += __shfl_xor(az0,1); az1 += __shfl_xor(az1,1);
            ar0 += __shfl_xor(ar0,1); ar1 += __shfl_xor(ar1,1);
            float z0 = sigmoidf_(__half2float(pxcur[        j]) + az0);
            float z1 = sigmoidf_(__half2float(pxcur[768   + j]) + az1);
            float r0 = sigmoidf_(__half2float(pxcur[256   + j]) + ar0);
            float r1 = sigmoidf_(__half2float(pxcur[768+256+j]) + ar1);
            if(kh==0){
                ((__half*)(rhUb      ))[hidx] = __float2half(r0*hreg0);
                ((__half*)(rhUb + 136))[hidx] = __float2half(r1*hreg1);
            }
            __syncthreads();
            float ah0=0.f, ah1=0.f;
            #pragma unroll
            for(int q=0;q<64;q+=4){
                uint4 rv0 = *(const uint4*)(r0p + q);
                uint4 rv1 = *(const uint4*)(r1p + q);
                ah0=d2(wh[q+0],rv0.x,ah0); ah1=d2(wh[q+0],rv1.x,ah1);
                ah0=d2(wh[q+1],rv0.y,ah0); ah1=d2(wh[q+1],rv1.y,ah1);
                ah0=d2(wh[q+2],rv0.z,ah0); ah1=d2(wh[q+2],rv1.z,ah1);
                ah0=d2(wh[q+3],rv0.w,ah0); ah1=d2(wh[q+3],rv1.w,ah1);
            }
            ah0 += __shfl_xor(ah0,1); ah1 += __shfl_xor(ah1,1);
            float ht0 = tanhf_(__half2float(pxcur[512    + j]) + ah0);
            float ht1 = tanhf_(__half2float(pxcur[768+512+j]) + ah1);
            hreg0 = (1.f - z0)*hreg0 + z0*ht0;
            hreg1 = (1.f - z1)*hreg1 + z1*ht1;
            if(kh==0){
                ((__half*)(hUb      ))[hidx] = __float2half(hreg0);
                ((__half*)(hUb + 136))[hidx] = __float2half(hreg1);
            }
            if(s < 63){
                pxsb[(cur^1)*768 + t] = nf0;
                if(t < 256) pxsb[(cur^1)*768 + t+512] = nf1;
            }
            __syncthreads();
        }
        if(kh==0){
            hstate[(b0+0)*HH + j] = hreg0;
            hstate[(b0+1)*HH + j] = hreg1;
        }
    } else {
        // ================= projm body, chunk chunkW -> pxW (lTc=6) =================
        uint4* AsU = (uint4*)smem;        // 16KB
        uint4* BsU = AsU + 1024;          // 16KB
        const int pb   = blockIdx.x - 256;
        const int rblk = (pb & 255) * 128;
        const int ct0  = (pb >> 8) * 128;
        const int etid = tid & 255;
        const bool act = tid < 256;

        const int row = etid >> 1;
        const int hf  = etid & 1;
        const int ar  = rblk + row;
        const long grow = ((long)(ar >> 6))*TT + ((long)chunkW << 6) + (ar & 63);
        const uint4* gA = (const uint4*)(xc + grow*384);
        const uint4* gB = (const uint4*)(Wcat + (size_t)(ct0 + row)*384);

        const int wv = (tid >> 6) & 3;    // clamp: upper waves duplicate lower
        const int wm = wv >> 1, wn = wv & 1;
        const int l  = tid & 63;
        const int g  = l >> 4, r16 = l & 15;

        f32x4 acc[4][4];
        #pragma unroll
        for(int i=0;i<4;++i)
            #pragma unroll
            for(int jj=0;jj<4;++jj) acc[i][jj] = (f32x4){0.f,0.f,0.f,0.f};

        for(int bk=0; bk<6; ++bk){
            uint4 av[4], bv[4];
            #pragma unroll
            for(int u=0;u<4;++u){ av[u] = gA[bk*8 + hf*4 + u]; bv[u] = gB[bk*8 + hf*4 + u]; }
            if(bk) __syncthreads();
            #pragma unroll
            for(int u=0;u<4;++u){
                int uu = hf*4 + u;
                AsU[row*8 + (uu ^ (row&7))] = av[u];   // dup writes same val: benign
                BsU[row*8 + (uu ^ (row&7))] = bv[u];
            }
            __syncthreads();
            #pragma unroll
            for(int ks=0;ks<2;++ks){
                f16x8 af[4], bf[4];
                #pragma unroll
                for(int mf=0;mf<4;++mf){
                    int rr = wm*64 + mf*16 + r16;
                    af[mf] = __builtin_bit_cast(f16x8, AsU[rr*8 + ((ks*4+g) ^ (rr&7))]);
                }
                #pragma unroll
                for(int nf=0;nf<4;++nf){
                    int rr = wn*64 + nf*16 + r16;
                    bf[nf] = __builtin_bit_cast(f16x8, BsU[rr*8 + ((ks*4+g) ^ (rr&7))]);
                }
                #pragma unroll
                for(int mf=0;mf<4;++mf)
                    #pragma unroll
                    for(int nf=0;nf<4;++nf)
                        acc[mf][nf] = __builtin_amdgcn_mfma_f32_16x16x32_f16(af[mf], bf[nf], acc[mf][nf], 0,0,0);
            }
        }
        if(act){
            #pragma unroll
            for(int nf=0; nf<4; ++nf){
                int col = ct0 + wn*64 + nf*16 + r16;
                float bb = bcat[col];
                #pragma unroll
                for(int mf=0; mf<4; ++mf){
                    int r0 = rblk + wm*64 + mf*16 + g*4;
                    f32x4 v = acc[mf][nf];
                    #pragma unroll
                    for(int e=0;e<4;++e)
                        pxW[(size_t)(r0+e)*768 + col] = __float2half(v[e] + bb);
                }
            }
        }
    }
}

// ---- LayerNorm + output projection ----
__global__ __launch_bounds__(256) void k_lnout(const float* __restrict__ hbuf,
    const float* __restrict__ lng, const float* __restrict__ lnb,
    const float* __restrict__ Wo, const float* __restrict__ bo,
    float* __restrict__ out){
    __shared__ __align__(16) float ln_s[HH];
    __shared__ float red[8];
    const int b = blockIdx.x, j = threadIdx.x;
    const float v = hbuf[(long)b*HH + j];
    float s = v, ss = v*v;
    const int lane = j & 63, w = j >> 6;
    for(int off=32; off>0; off>>=1){
        s  += __shfl_down(s,  off);
        ss += __shfl_down(ss, off);
    }
    if(lane == 0){ red[w] = s; red[4+w] = ss; }
    __syncthreads();
    float tot  = red[0]+red[1]+red[2]+red[3];
    float tot2 = red[4]+red[5]+red[6]+red[7];
    float mu  = tot  * (1.0f/HH);
    float var = tot2 * (1.0f/HH) - mu*mu;
    float rstd = rsqrtf(var + 1e-5f);
    ln_s[j] = (v - mu)*rstd*lng[j] + lnb[j];
    __syncthreads();
    if(j < OO){
        float acc = bo[j];
        const float4* w4 = (const float4*)(Wo + j*HH);
        const float4* l4 = (const float4*)ln_s;
        for(int k4=0;k4<HH/4;++k4){
            float4 wv = w4[k4], c = l4[k4];
            acc += wv.x*c.x + wv.y*c.y + wv.z*c.z + wv.w*c.w;
        }
        out[(long)b*OO + j] = acc;
    }
}

// ================= fallback path (round-0, proven, ~68MB ws) =================

__global__ __launch_bounds__(128) void k_emb_o(const float* __restrict__ x,
                                               const float* __restrict__ W,
                                               const float* __restrict__ bias,
                                               float* __restrict__ x1){
    __shared__ __align__(16) float xs[8][DD];
    const int j = threadIdx.x;
    const long row0 = (long)blockIdx.x * 32;
    const float bj = bias[j];
    const float4* W4 = (const float4*)(W + j*DD);
    for(int g=0; g<4; ++g){
        const long rbase = row0 + g*8;
        for(int r=0;r<8;++r) xs[r][j] = x[(rbase+r)*DD + j];
        __syncthreads();
        float acc[8];
        #pragma unroll
        for(int r=0;r<8;++r) acc[r] = bj;
        for(int k4=0;k4<DD/4;++k4){
            float4 w = W4[k4];
            #pragma unroll
            for(int r=0;r<8;++r){
                float4 c = ((const float4*)xs[r])[k4];
                acc[r] += c.x*w.x + c.y*w.y + c.z*w.z + c.w*w.w;
            }
        }
        for(int r=0;r<8;++r) x1[(rbase+r)*DD + j] = acc[r];
        __syncthreads();
    }
}

__global__ __launch_bounds__(128) void k_mean_o(const float* __restrict__ x1,
                                                float* __restrict__ xmean){
    const int j = threadIdx.x;
    const int b = blockIdx.x;
    const float* p = x1 + (long)b*TT*DD + j;
    float s = 0.f;
    for(int t=0;t<TT;++t) s += p[(long)t*DD];
    xmean[b*DD + j] = s * (1.0f/TT);
}

__global__ __launch_bounds__(128) void k_gate_o(float* __restrict__ xf,
    const float* __restrict__ xmask, const float* __restrict__ xdelta,
    const float* __restrict__ noise,
    const float* __restrict__ Wd1, const float* __restrict__ bd1,
    const float* __restrict__ Wd2, const float* __restrict__ bd2,
    const float* __restrict__ Wc,  const float* __restrict__ bc,
    const float* __restrict__ xmean){
    __shared__ __align__(16) float ds[8][DD];
    __shared__ __align__(16) float t1s[8][DD];
    __shared__ __align__(16) float xhs[8][DD];
    const int j = threadIdx.x;
    const long row0 = (long)blockIdx.x * 32;
    const int b = (int)(row0 >> 8);
    const float xm = xmean[b*DD + j];
    const float b1 = bd1[j], b2 = bd2[j], bcj = bc[j];
    const float4* Wd1_4 = (const float4*)(Wd1 + j*DD);
    const float4* Wd2_4 = (const float4*)(Wd2 + j*DD);
    const float4* Wc_4  = (const float4*)(Wc  + j*2*DD);
    for(int g=0; g<4; ++g){
        const long rbase = row0 + g*8;
        for(int r=0;r<8;++r)
            ds[r][j] = fminf(fmaxf(xdelta[(rbase+r)*DD + j], 0.f), 100.f);
        __syncthreads();
        float acc[8];
        #pragma unroll
        for(int r=0;r<8;++r) acc[r] = b1;
        for(int k4=0;k4<DD/4;++k4){
            float4 w = Wd1_4[k4];
            #pragma unroll
            for(int r=0;r<8;++r){
                float4 c = ((const float4*)ds[r])[k4];
                acc[r] += c.x*w.x + c.y*w.y + c.z*w.z + c.w*w.w;
            }
        }
        for(int r=0;r<8;++r) t1s[r][j] = fmaxf(acc[r], 0.f);
        __syncthreads();
        #pragma unroll
        for(int r=0;r<8;++r) acc[r] = b2;
        for(int k4=0;k4<DD/4;++k4){
            float4 w = Wd2_4[k4];
            #pragma unroll
            for(int r=0;r<8;++r){
                float4 c = ((const float4*)t1s[r])[k4];
                acc[r] += c.x*w.x + c.y*w.y + c.z*w.z + c.w*w.w;
            }
        }
        for(int r=0;r<8;++r){
            float gmm = sigmoidf_(acc[r]);
            float m  = xmask[(rbase+r)*DD + j];
            float xv = xf[(rbase+r)*DD + j];
            xhs[r][j] = m*xv + (1.f-m)*gmm*xm;
        }
        __syncthreads();
        #pragma unroll
        for(int r=0;r<8;++r) acc[r] = bcj;
        for(int k4=0;k4<DD/4;++k4){
            float4 w = Wc_4[k4];
            #pragma unroll
            for(int r=0;r<8;++r){
                float4 c = ((const float4*)xhs[r])[k4];
                acc[r] += c.x*w.x + c.y*w.y + c.z*w.z + c.w*w.w;
            }
        }
        for(int k4=0;k4<DD/4;++k4){
            float4 w = Wc_4[DD/4 + k4];
            #pragma unroll
            for(int r=0;r<8;++r){
                float4 c = ((const float4*)ds[r])[k4];
                acc[r] += c.x*w.x + c.y*w.y + c.z*w.z + c.w*w.w;
            }
        }
        for(int r=0;r<8;++r){
            float conf = sigmoidf_(acc[r]);
            float xh = xhs[r][j];
            float nz = noise[(rbase+r)*DD + j];
            xf[(rbase+r)*DD + j] = xh*conf + nz*(1.f-conf);
        }
        __syncthreads();
    }
}

__global__ __launch_bounds__(1024) void k_gru_o(const float* __restrict__ xf,
    const float* __restrict__ xmask, const float* __restrict__ xdelta,
    const float* __restrict__ Wz, const float* __restrict__ bz,
    const float* __restrict__ Wr, const float* __restrict__ br,
    const float* __restrict__ Wh, const float* __restrict__ bh,
    float* __restrict__ hout){
    __shared__ __align__(16) float xcs[4][KH];
    __shared__ __align__(16) float rh[4][HH];
    const int tid = threadIdx.x;
    const int j  = tid & 255;
    const int bl = tid >> 8;
    const long bbase = (long)blockIdx.x * 4;
    xcs[bl][384 + j] = 0.f;
    const float bzj = bz[j], brj = br[j], bhj = bh[j];
    const float4* Wz4 = (const float4*)(Wz + (long)j*KH);
    const float4* Wr4 = (const float4*)(Wr + (long)j*KH);
    const float4* Wh4 = (const float4*)(Wh + (long)j*KH);
    __syncthreads();
    for(int t=0;t<TT;++t){
        if(tid < 4*DD){
            int sb = tid >> 7, k = tid & 127;
            long row = (bbase + sb)*TT + t;
            xcs[sb][k]       = xf[row*DD + k];
            xcs[sb][128 + k] = xmask[row*DD + k];
            xcs[sb][256 + k] = fminf(fmaxf(xdelta[row*DD + k], 0.f), 100.f);
        }
        __syncthreads();
        const float4* cb = (const float4*)xcs[bl];
        float az = bzj, ar = brj;
        for(int k4=0;k4<KH/4;++k4){
            float4 wz = Wz4[k4], wrr = Wr4[k4];
            float4 v = cb[k4];
            az += v.x*wz.x + v.y*wz.y + v.z*wz.z + v.w*wz.w;
            ar += v.x*wrr.x + v.y*wrr.y + v.z*wrr.z + v.w*wrr.w;
        }
        float z = sigmoidf_(az);
        float r = sigmoidf_(ar);
        rh[bl][j] = r * xcs[bl][384 + j];
        __syncthreads();
        float ah = bhj;
        for(int k4=0;k4<96;++k4){
            float4 wh = Wh4[k4];
            float4 v = cb[k4];
            ah += v.x*wh.x + v.y*wh.y + v.z*wh.z + v.w*wh.w;
        }
        const float4* rp = (const float4*)rh[bl];
        for(int k4=0;k4<64;++k4){
            float4 wh = Wh4[96 + k4];
            float4 v = rp[k4];
            ah += v.x*wh.x + v.y*wh.y + v.z*wh.z + v.w*wh.w;
        }
        float ht = tanhf(ah);
        float hold = xcs[bl][384 + j];
        float hn = (1.f - z)*hold + z*ht;
        xcs[bl][384 + j] = hn;
        __syncthreads();
    }
    hout[(bbase + bl)*HH + j] = xcs[bl][384 + j];
}

// ================= launch =================

extern "C" void kernel_launch(void* const* d_in, const int* in_sizes, int n_in,
                              void* d_out, int out_size, void* d_ws, size_t ws_size,
                              hipStream_t stream){
    const float* x      = (const float*)d_in[0];
    const float* xmask  = (const float*)d_in[1];
    const float* xdelta = (const float*)d_in[2];
    const float* noise  = (const float*)d_in[3];
    const float* W_emb  = (const float*)d_in[4];
    const float* b_emb  = (const float*)d_in[5];
    const float* W_d1   = (const float*)d_in[6];
    const float* b_d1   = (const float*)d_in[7];
    const float* W_d2   = (const float*)d_in[8];
    const float* b_d2   = (const float*)d_in[9];
    const float* W_c    = (const float*)d_in[10];
    const float* b_c    = (const float*)d_in[11];
    const float* W_z    = (const float*)d_in[12];
    const float* b_z    = (const float*)d_in[13];
    const float* W_r    = (const float*)d_in[14];
    const float* b_r    = (const float*)d_in[15];
    const float* W_h    = (const float*)d_in[16];
    const float* b_h    = (const float*)d_in[17];
    const float* ln_g   = (const float*)d_in[18];
    const float* ln_b   = (const float*)d_in[19];
    const float* W_o    = (const float*)d_in[20];
    const float* b_o    = (const float*)d_in[21];
    float* out = (float*)d_out;
    char* ws = (char*)d_ws;

    const size_t need_dual = SZ_XC + 2*SZ_PX64 + TAIL_SZ;   // ~203.2 MB (ws>=236.6 proven)

    if(ws_size >= need_dual){
        __half* xc    = (__half*)(ws);
        char*   p     = ws + SZ_XC;
        __half* pxA   = (__half*)p;              p += SZ_PX64;
        __half* pxB   = (__half*)p;              p += SZ_PX64;
        __half* Wcat  = (__half*)p;              p += 589824;
        __half* Wrec  = (__half*)p;              p += 393216;
        float*  bcat  = (float*)p;               p += 3072;
        float*  xmean = (float*)p;               p += 262144;
        float*  hstate= (float*)p;               p += 524288;
        __half* Wembh = (__half*)p;              p += 32768;
        __half* Wd1h  = (__half*)p;              p += 32768;
        __half* Wd2h  = (__half*)p;              p += 32768;
        __half* Wch   = (__half*)p;

        k_wprep<<<dim3(768),   dim3(128), 0, stream>>>(W_z,W_r,W_h,b_z,b_r,b_h, Wcat, Wrec, bcat);
        k_cvt  <<<dim3(128),   dim3(256), 0, stream>>>(W_emb, W_d1, W_d2, W_c, Wembh, Wd1h, Wd2h, Wch);
        k_meanx<<<dim3(BB),    dim3(256), 0, stream>>>(x, W_emb, b_emb, xmean);
        k_embgate<<<dim3(BT/128), dim3(256), 0, stream>>>(x, xmask, xdelta, noise,
                                                          Wembh, b_emb, Wd1h, b_d1,
                                                          Wd2h, b_d2, Wch, b_c, xmean, xc);
        // pipelined: projm(c0) ; [gruc(c) || projm(c+1)] x3 ; gruc(c3)
        k_projm<<<dim3(256, 6), dim3(256), 0, stream>>>(xc, Wcat, bcat, pxA, 6, 0);
        k_fused<<<dim3(1792), dim3(512), 0, stream>>>(pxA, pxB, xc, Wcat, bcat, Wrec, hstate, 1, 1);
        k_fused<<<dim3(1792), dim3(512), 0, stream>>>(pxB, pxA, xc, Wcat, bcat, Wrec, hstate, 0, 2);
        k_fused<<<dim3(1792), dim3(512), 0, stream>>>(pxA, pxB, xc, Wcat, bcat, Wrec, hstate, 0, 3);
        k_gruc <<<dim3(256), dim3(512), 0, stream>>>(pxB, Wrec, hstate, 64, 0);
        k_lnout<<<dim3(BB), dim3(256), 0, stream>>>(hstate, ln_g, ln_b, W_o, b_o, out);
    } else {
        // serial single-buffer path (round-12 behavior, Tc from {64,32})
        int Tc = 0, lTc = 0;
        const int cand[2]  = {64, 32};
        const int lcand[2] = {6, 5};
        for(int i=0;i<2;++i){
            size_t need = SZ_XC + (size_t)cand[i]*786432 + TAIL_SZ;
            if(ws_size >= need){ Tc = cand[i]; lTc = lcand[i]; break; }
        }
        if(Tc > 0){
            __half* xc    = (__half*)(ws);
            char*   p     = ws + SZ_XC;
            __half* pxc   = (__half*)p;              p += (size_t)Tc*786432;
            __half* Wcat  = (__half*)p;              p += 589824;
            __half* Wrec  = (__half*)p;              p += 393216;
            float*  bcat  = (float*)p;               p += 3072;
            float*  xmean = (float*)p;               p += 262144;
            float*  hstate= (float*)p;               p += 524288;
            __half* Wembh = (__half*)p;              p += 32768;
            __half* Wd1h  = (__half*)p;              p += 32768;
            __half* Wd2h  = (__half*)p;              p += 32768;
            __half* Wch   = (__half*)p;

            k_wprep<<<dim3(768),   dim3(128), 0, stream>>>(W_z,W_r,W_h,b_z,b_r,b_h, Wcat, Wrec, bcat);
            k_cvt  <<<dim3(128),   dim3(256), 0, stream>>>(W_emb, W_d1, W_d2, W_c, Wembh, Wd1h, Wd2h, Wch);
            k_meanx<<<dim3(BB),    dim3(256), 0, stream>>>(x, W_emb, b_emb, xmean);
            k_embgate<<<dim3(BT/128), dim3(256), 0, stream>>>(x, xmask, xdelta, noise,
                                                              Wembh, b_emb, Wd1h, b_d1,
                                                              Wd2h, b_d2, Wch, b_c, xmean, xc);
            const int nchunk = TT / Tc;
            for(int c=0; c<nchunk; ++c){
                k_projm<<<dim3(BB*Tc/128, 6), dim3(256), 0, stream>>>(xc, Wcat, bcat, pxc, lTc, c);
                k_gruc <<<dim3(BB/2), dim3(512), 0, stream>>>(pxc, Wrec, hstate, Tc, c==0 ? 1 : 0);
            }
            k_lnout<<<dim3(BB), dim3(256), 0, stream>>>(hstate, ln_g, ln_b, W_o, b_o, out);
        } else {
            float* xf    = (float*)ws;
            float* xmean = (float*)(ws + (size_t)BT*DD*4);
            float* hbuf  = (float*)(ws + (size_t)BT*DD*4 + (size_t)BB*DD*4);
            k_emb_o  <<<dim3(BT/32), dim3(128), 0, stream>>>(x, W_emb, b_emb, xf);
            k_mean_o <<<dim3(BB),    dim3(128), 0, stream>>>(xf, xmean);
            k_gate_o <<<dim3(BT/32), dim3(128), 0, stream>>>(xf, xmask, xdelta, noise,
                                                             W_d1,b_d1,W_d2,b_d2,W_c,b_c, xmean);
            k_gru_o  <<<dim3(BB/4),  dim3(1024),0, stream>>>(xf, xmask, xdelta,
                                                             W_z,b_z,W_r,b_r,W_h,b_h, hbuf);
            k_lnout  <<<dim3(BB),    dim3(256), 0, stream>>>(hbuf, ln_g, ln_b, W_o, b_o, out);
        }
    }
}

// Round 14
// 1350.607 us; speedup vs baseline: 1.1938x; 1.1938x over previous
//
#include <hip/hip_runtime.h>
#include <hip/hip_fp16.h>
#include <math.h>

#define BB 512
#define TT 256
#define DD 128
#define HH 256
#define OO 128
#define KH 640   // 3*D + H
#define BT (BB*TT)

typedef unsigned int uint_t;
typedef _Float16 f16x8 __attribute__((ext_vector_type(8)));
typedef float f32x4 __attribute__((ext_vector_type(4)));

__device__ __forceinline__ float sigmoidf_(float x){ return 1.0f/(1.0f+__expf(-x)); }
__device__ __forceinline__ float tanhf_(float x){ float e = __expf(-2.0f*x); return 2.0f/(1.0f+e) - 1.0f; }
__device__ __forceinline__ float clipd_(float x){ return fminf(fmaxf(x, 0.f), 100.f); }

typedef _Float16 h2v __attribute__((ext_vector_type(2)));
__device__ __forceinline__ float d2(uint_t a, uint_t b, float c){
#if __has_builtin(__builtin_amdgcn_fdot2)
    return __builtin_amdgcn_fdot2(__builtin_bit_cast(h2v, a), __builtin_bit_cast(h2v, b), c, false);
#else
    __half2 ha = __builtin_bit_cast(__half2, a);
    __half2 hb = __builtin_bit_cast(__half2, b);
    return c + __half2float(ha.x)*__half2float(hb.x) + __half2float(ha.y)*__half2float(hb.y);
#endif
}
__device__ __forceinline__ uint_t pack2(float a, float b){
    __half2 h; h.x = __float2half(a); h.y = __float2half(b);
    return __builtin_bit_cast(uint_t, h);
}

// ---- ws layout ----
static const size_t SZ_XC   = (size_t)BT*384*2;
static const size_t TAIL_SZ = 589824 + 393216 + 3072 + 262144 + 524288 + 32768*3 + 65536;

// ---- weight prep: GRU weights f32 -> f16, split cat(384)/rec(256) ----
__global__ __launch_bounds__(128) void k_wprep(const float* __restrict__ Wz, const float* __restrict__ Wr,
                                               const float* __restrict__ Wh, const float* __restrict__ bz,
                                               const float* __restrict__ br, const float* __restrict__ bh,
                                               __half* __restrict__ Wcat, __half* __restrict__ Wrec,
                                               float* __restrict__ bcat){
    int gj = blockIdx.x; int j = gj & 255;
    const float* src  = (gj < 256 ? Wz : (gj < 512 ? Wr : Wh)) + (size_t)j*KH;
    const float* bsrc = (gj < 256 ? bz : (gj < 512 ? br : bh));
    for(int k=threadIdx.x; k<384; k+=128) Wcat[(size_t)gj*384 + k] = __float2half(src[k]);
    for(int k=threadIdx.x; k<256; k+=128) Wrec[(size_t)gj*256 + k] = __float2half(src[384+k]);
    if(threadIdx.x==0) bcat[gj] = bsrc[j];
}

// ---- small weights f32 -> f16 ----
__global__ __launch_bounds__(256) void k_cvt(const float* __restrict__ a, const float* __restrict__ b,
                                             const float* __restrict__ c, const float* __restrict__ d,
                                             __half* __restrict__ oa, __half* __restrict__ ob,
                                             __half* __restrict__ oc, __half* __restrict__ od){
    int i = blockIdx.x*256 + threadIdx.x;
    if(i < 16384){
        oa[i] = __float2half(a[i]);
        ob[i] = __float2half(b[i]);
        oc[i] = __float2half(c[i]);
    }
    od[i] = __float2half(d[i]);
}

// ---- xmean via linearity: mean_t(x@W^T+b) = (mean_t x)@W^T + b ----
__global__ __launch_bounds__(256) void k_meanx(const float* __restrict__ x,
                                               const float* __restrict__ Wemb,
                                               const float* __restrict__ bemb,
                                               float* __restrict__ xmean){
    __shared__ float red[2][128];
    __shared__ __align__(16) float xr[128];
    const int tid = threadIdx.x;
    const int b = blockIdx.x;
    const int col = tid & 127, hf = tid >> 7;
    float s = 0.f;
    const float* px = x + ((size_t)b*TT + hf*128)*DD + col;
    for(int t=0;t<128;++t) s += px[(size_t)t*DD];
    red[hf][col] = s;
    __syncthreads();
    if(tid < 128) xr[tid] = (red[0][tid] + red[1][tid]) * (1.0f/TT);
    __syncthreads();
    if(tid < 128){
        float acc = bemb[tid];
        const float4* wr = (const float4*)(Wemb + tid*DD);
        const float4* xv = (const float4*)xr;
        for(int k4=0;k4<32;++k4){
            float4 w = wr[k4], v = xv[k4];
            acc += w.x*v.x + w.y*v.y + w.z*v.z + w.w*v.w;
        }
        xmean[b*DD + tid] = acc;
    }
}

// ---- fused emb + gate chain (MFMA): fills xc row = [x_final | mask | delta] ----
__global__ __launch_bounds__(256,2) void k_embgate(const float* __restrict__ x,
    const float* __restrict__ xmask, const float* __restrict__ xdelta,
    const float* __restrict__ noise,
    const __half* __restrict__ Wembh, const float* __restrict__ bemb,
    const __half* __restrict__ Wd1h, const float* __restrict__ bd1,
    const __half* __restrict__ Wd2h, const float* __restrict__ bd2,
    const __half* __restrict__ Wch,  const float* __restrict__ bc,
    const float* __restrict__ xmean, __half* __restrict__ xc){
    __shared__ __align__(16) uint4 TaU[128*16];
    __shared__ __align__(16) uint4 TdU[128*16];
    __half* TaH = (__half*)TaU;
    const int tid = threadIdx.x;
    const long row0 = (long)blockIdx.x*128;
    const int b = (int)(row0 >> 8);

    {
        const int srow = tid>>1, shalf = tid&1;
        const long gr = row0 + srow;
        const float4* gx = (const float4*)(x      + gr*DD + shalf*64);
        const float4* gd = (const float4*)(xdelta + gr*DD + shalf*64);
        const float4* gm = (const float4*)(xmask  + gr*DD + shalf*64);
        uint4* xcu = (uint4*)(xc + gr*384);
        #pragma unroll
        for(int u=0;u<8;++u){
            float4 a = gx[u*2], q = gx[u*2+1];
            uint4 pk;
            pk.x = pack2(a.x,a.y); pk.y = pack2(a.z,a.w);
            pk.z = pack2(q.x,q.y); pk.w = pack2(q.z,q.w);
            int unit = shalf*8 + u;
            TaU[srow*16 + (unit ^ (srow&7))] = pk;
        }
        #pragma unroll
        for(int u=0;u<8;++u){
            float4 a = gd[u*2], q = gd[u*2+1];
            uint4 pk;
            pk.x = pack2(clipd_(a.x), clipd_(a.y));
            pk.y = pack2(clipd_(a.z), clipd_(a.w));
            pk.z = pack2(clipd_(q.x), clipd_(q.y));
            pk.w = pack2(clipd_(q.z), clipd_(q.w));
            int unit = shalf*8 + u;
            TdU[srow*16 + (unit ^ (srow&7))] = pk;
            xcu[32 + unit] = pk;
        }
        #pragma unroll
        for(int u=0;u<8;++u){
            float4 a = gm[u*2], q = gm[u*2+1];
            uint4 pk;
            pk.x = pack2(a.x,a.y); pk.y = pack2(a.z,a.w);
            pk.z = pack2(q.x,q.y); pk.w = pack2(q.z,q.w);
            xcu[16 + shalf*8 + u] = pk;
        }
    }
    __syncthreads();

    const int wv = tid>>6, lane = tid&63, g = lane>>4, r16 = lane&15;
    const int wrow0 = wv*32;
    const uint4* WeU = (const uint4*)Wembh;
    const uint4* W1U = (const uint4*)Wd1h;
    const uint4* W2U = (const uint4*)Wd2h;
    const uint4* WcU = (const uint4*)Wch;
    f32x4 acc[2][8];

    // stage 1: x1 -> registers
    f32x4 x1f[2][8];
    #pragma unroll
    for(int i=0;i<2;++i)
        #pragma unroll
        for(int jj=0;jj<8;++jj) x1f[i][jj] = (f32x4){0.f,0.f,0.f,0.f};
    #pragma unroll
    for(int ks=0;ks<4;++ks){
        f16x8 af[2], bf[8];
        #pragma unroll
        for(int mf=0;mf<2;++mf){
            int rr = wrow0 + mf*16 + r16;
            af[mf] = __builtin_bit_cast(f16x8, TaU[rr*16 + ((ks*4+g) ^ (rr&7))]);
        }
        #pragma unroll
        for(int nf=0;nf<8;++nf){
            int col = nf*16 + r16;
            bf[nf] = __builtin_bit_cast(f16x8, WeU[col*16 + ks*4 + g]);
        }
        #pragma unroll
        for(int mf=0;mf<2;++mf)
            #pragma unroll
            for(int nf=0;nf<8;++nf)
                x1f[mf][nf] = __builtin_amdgcn_mfma_f32_16x16x32_f16(af[mf], bf[nf], x1f[mf][nf], 0,0,0);
    }
    #pragma unroll
    for(int nf=0;nf<8;++nf){
        float bb = bemb[nf*16 + r16];
        #pragma unroll
        for(int mf=0;mf<2;++mf)
            #pragma unroll
            for(int e=0;e<4;++e) x1f[mf][nf][e] += bb;
    }

    // stage 2: t1 = relu(d @ Wd1^T + b1) -> TaU
    #pragma unroll
    for(int i=0;i<2;++i)
        #pragma unroll
        for(int jj=0;jj<8;++jj) acc[i][jj] = (f32x4){0.f,0.f,0.f,0.f};
    #pragma unroll
    for(int ks=0;ks<4;++ks){
        f16x8 af[2], bf[8];
        #pragma unroll
        for(int mf=0;mf<2;++mf){
            int rr = wrow0 + mf*16 + r16;
            af[mf] = __builtin_bit_cast(f16x8, TdU[rr*16 + ((ks*4+g) ^ (rr&7))]);
        }
        #pragma unroll
        for(int nf=0;nf<8;++nf){
            int col = nf*16 + r16;
            bf[nf] = __builtin_bit_cast(f16x8, W1U[col*16 + ks*4 + g]);
        }
        #pragma unroll
        for(int mf=0;mf<2;++mf)
            #pragma unroll
            for(int nf=0;nf<8;++nf)
                acc[mf][nf] = __builtin_amdgcn_mfma_f32_16x16x32_f16(af[mf], bf[nf], acc[mf][nf], 0,0,0);
    }
    #pragma unroll
    for(int nf=0;nf<8;++nf){
        int col = nf*16 + r16;
        float bb = bd1[col];
        int u = col>>3, cl = col&7;
        #pragma unroll
        for(int mf=0;mf<2;++mf){
            int rowb = wrow0 + mf*16 + g*4;
            f32x4 v = acc[mf][nf];
            #pragma unroll
            for(int e=0;e<4;++e){
                int rr = rowb + e;
                float tt = v[e] + bb; tt = tt > 0.f ? tt : 0.f;
                TaH[(rr*16 + (u ^ (rr&7)))*8 + cl] = __float2half(tt);
            }
        }
    }

    // stage 3: gamma
    #pragma unroll
    for(int i=0;i<2;++i)
        #pragma unroll
        for(int jj=0;jj<8;++jj) acc[i][jj] = (f32x4){0.f,0.f,0.f,0.f};
    #pragma unroll
    for(int ks=0;ks<4;++ks){
        f16x8 af[2], bf[8];
        #pragma unroll
        for(int mf=0;mf<2;++mf){
            int rr = wrow0 + mf*16 + r16;
            af[mf] = __builtin_bit_cast(f16x8, TaU[rr*16 + ((ks*4+g) ^ (rr&7))]);
        }
        #pragma unroll
        for(int nf=0;nf<8;++nf){
            int col = nf*16 + r16;
            bf[nf] = __builtin_bit_cast(f16x8, W2U[col*16 + ks*4 + g]);
        }
        #pragma unroll
        for(int mf=0;mf<2;++mf)
            #pragma unroll
            for(int nf=0;nf<8;++nf)
                acc[mf][nf] = __builtin_amdgcn_mfma_f32_16x16x32_f16(af[mf], bf[nf], acc[mf][nf], 0,0,0);
    }

    // stage 4: x_hat -> TaU
    #pragma unroll
    for(int nf=0;nf<8;++nf){
        int col = nf*16 + r16;
        float b2 = bd2[col];
        float xm = xmean[b*DD + col];
        int u = col>>3, cl = col&7;
        #pragma unroll
        for(int mf=0;mf<2;++mf){
            int rowb = wrow0 + mf*16 + g*4;
            f32x4 v = acc[mf][nf];
            #pragma unroll
            for(int e=0;e<4;++e){
                int rr = rowb + e;
                long grow = row0 + rr;
                float m  = xmask[grow*DD + col];
                float gmm = sigmoidf_(v[e] + b2);
                float xh = m*x1f[mf][nf][e] + (1.f-m)*gmm*xm;
                TaH[(rr*16 + (u ^ (rr&7)))*8 + cl] = __float2half(xh);
            }
        }
    }

    // stage 5: conf
    #pragma unroll
    for(int i=0;i<2;++i)
        #pragma unroll
        for(int jj=0;jj<8;++jj) acc[i][jj] = (f32x4){0.f,0.f,0.f,0.f};
    #pragma unroll
    for(int ks=0;ks<4;++ks){
        f16x8 af[2], bf[8];
        #pragma unroll
        for(int mf=0;mf<2;++mf){
            int rr = wrow0 + mf*16 + r16;
            af[mf] = __builtin_bit_cast(f16x8, TaU[rr*16 + ((ks*4+g) ^ (rr&7))]);
        }
        #pragma unroll
        for(int nf=0;nf<8;++nf){
            int col = nf*16 + r16;
            bf[nf] = __builtin_bit_cast(f16x8, WcU[col*32 + ks*4 + g]);
        }
        #pragma unroll
        for(int mf=0;mf<2;++mf)
            #pragma unroll
            for(int nf=0;nf<8;++nf)
                acc[mf][nf] = __builtin_amdgcn_mfma_f32_16x16x32_f16(af[mf], bf[nf], acc[mf][nf], 0,0,0);
    }
    #pragma unroll
    for(int ks=0;ks<4;++ks){
        f16x8 af[2], bf[8];
        #pragma unroll
        for(int mf=0;mf<2;++mf){
            int rr = wrow0 + mf*16 + r16;
            af[mf] = __builtin_bit_cast(f16x8, TdU[rr*16 + ((ks*4+g) ^ (rr&7))]);
        }
        #pragma unroll
        for(int nf=0;nf<8;++nf){
            int col = nf*16 + r16;
            bf[nf] = __builtin_bit_cast(f16x8, WcU[col*32 + 16 + ks*4 + g]);
        }
        #pragma unroll
        for(int mf=0;mf<2;++mf)
            #pragma unroll
            for(int nf=0;nf<8;++nf)
                acc[mf][nf] = __builtin_amdgcn_mfma_f32_16x16x32_f16(af[mf], bf[nf], acc[mf][nf], 0,0,0);
    }

    // stage 6: x_final
    #pragma unroll
    for(int nf=0;nf<8;++nf){
        int col = nf*16 + r16;
        float bcc = bc[col];
        int u = col>>3, cl = col&7;
        #pragma unroll
        for(int mf=0;mf<2;++mf){
            int rowb = wrow0 + mf*16 + g*4;
            f32x4 v = acc[mf][nf];
            #pragma unroll
            for(int e=0;e<4;++e){
                int rr = rowb + e;
                long grow = row0 + rr;
                float conf = sigmoidf_(v[e] + bcc);
                float xh = __half2float(TaH[(rr*16 + (u ^ (rr&7)))*8 + cl]);
                float nz = noise[grow*DD + col];
                xc[grow*384 + col] = __float2half(xh*conf + nz*(1.f-conf));
            }
        }
    }
}

// ---- MFMA projection: px[b*Tc+tl][768] = xc_chunk @ Wcat^T + bcat ----
__global__ __launch_bounds__(256) void k_projm(const __half* __restrict__ xc,
                                               const __half* __restrict__ Wcat,
                                               const float* __restrict__ bcat,
                                               __half* __restrict__ px,
                                               int lTc, int chunk){
    __shared__ __align__(16) __half As[128*64];
    __shared__ __align__(16) __half Bs[128*64];
    const int tid = threadIdx.x;
    const int rblk = blockIdx.x * 128;
    const int ct0  = blockIdx.y * 128;
    const int mTc = (1<<lTc) - 1;

    const int row = tid >> 1;
    const int hf  = tid & 1;
    const int ar  = rblk + row;
    const long grow = ((long)(ar >> lTc))*TT + ((long)chunk << lTc) + (ar & mTc);
    const uint4* gA = (const uint4*)(xc + grow*384);
    const uint4* gB = (const uint4*)(Wcat + (size_t)(ct0 + row)*384);
    uint4* AsU = (uint4*)As;
    uint4* BsU = (uint4*)Bs;

    const int wv = tid >> 6;
    const int wm = wv >> 1, wn = wv & 1;
    const int l  = tid & 63;
    const int g  = l >> 4, r16 = l & 15;

    f32x4 acc[4][4];
    #pragma unroll
    for(int i=0;i<4;++i)
        #pragma unroll
        for(int jj=0;jj<4;++jj) acc[i][jj] = (f32x4){0.f,0.f,0.f,0.f};

    for(int bk=0; bk<6; ++bk){
        uint4 av[4], bv[4];
        #pragma unroll
        for(int u=0;u<4;++u){ av[u] = gA[bk*8 + hf*4 + u]; bv[u] = gB[bk*8 + hf*4 + u]; }
        if(bk) __syncthreads();
        #pragma unroll
        for(int u=0;u<4;++u){
            int uu = hf*4 + u;
            AsU[row*8 + (uu ^ (row&7))] = av[u];
            BsU[row*8 + (uu ^ (row&7))] = bv[u];
        }
        __syncthreads();
        #pragma unroll
        for(int ks=0;ks<2;++ks){
            f16x8 af[4], bf[4];
            #pragma unroll
            for(int mf=0;mf<4;++mf){
                int rr = wm*64 + mf*16 + r16;
                af[mf] = __builtin_bit_cast(f16x8, AsU[rr*8 + ((ks*4+g) ^ (rr&7))]);
            }
            #pragma unroll
            for(int nf=0;nf<4;++nf){
                int rr = wn*64 + nf*16 + r16;
                bf[nf] = __builtin_bit_cast(f16x8, BsU[rr*8 + ((ks*4+g) ^ (rr&7))]);
            }
            #pragma unroll
            for(int mf=0;mf<4;++mf)
                #pragma unroll
                for(int nf=0;nf<4;++nf)
                    acc[mf][nf] = __builtin_amdgcn_mfma_f32_16x16x32_f16(af[mf], bf[nf], acc[mf][nf], 0,0,0);
        }
    }
    #pragma unroll
    for(int nf=0; nf<4; ++nf){
        int col = ct0 + wn*64 + nf*16 + r16;
        float bb = bcat[col];
        #pragma unroll
        for(int mf=0; mf<4; ++mf){
            int r0 = rblk + wm*64 + mf*16 + g*4;
            f32x4 v = acc[mf][nf];
            #pragma unroll
            for(int e=0;e<4;++e)
                px[(size_t)(r0+e)*768 + col] = __float2half(v[e] + bb);
        }
    }
}

// ---- chunked GRU (round-6 body) ----
// Round-14 experiment: __launch_bounds__(512,1). Under (512,2) the 192
// weight-dwords/thread were VGPR-capped at 120 -> 393KB/step L2 re-stream
// (the ~6700 cyc/step term). Effective occupancy was already ~1 block/CU,
// so (512,1) costs nothing; if weights go resident the step floor drops to
// the ~6100-cyc LDS term. Revert this one line if >= 384us.
__global__ __launch_bounds__(512,1) void k_gruc(const __half* __restrict__ pxc,
                                                const __half* __restrict__ Wrec,
                                                float* __restrict__ hstate,
                                                int Tc, int init){
    __shared__ __align__(16) uint_t hU[2][136];
    __shared__ __align__(16) uint_t rhU[2][136];
    __shared__ __align__(16) uint_t pxs[2][768];
    const int t  = threadIdx.x;
    const int j  = t >> 1;
    const int kh = t & 1;
    const long b0 = (long)blockIdx.x*2;
    const uint_t* Wr32 = (const uint_t*)Wrec;

    uint_t wz[64], wr[64], wh[64];
    #pragma unroll
    for(int q=0;q<64;++q){
        wz[q] = Wr32[(size_t)(      j)*128 + kh*64 + q];
        wr[q] = Wr32[(size_t)(256 + j)*128 + kh*64 + q];
        wh[q] = Wr32[(size_t)(512 + j)*128 + kh*64 + q];
    }

    const uint_t* px32 = (const uint_t*)pxc;
    auto ldpx = [&](int tl, int f)->uint_t{
        int row = (f >= 384); int off = f - row*384;
        return px32[((size_t)(b0+row)*Tc + tl)*384 + off];
    };
    const int hidx = ((j>>7)*136) + (j&127);

    float hreg0, hreg1;
    if(init){ hreg0 = 0.f; hreg1 = 0.f; }
    else    { hreg0 = hstate[(b0+0)*HH + j]; hreg1 = hstate[(b0+1)*HH + j]; }
    if(kh==0){
        ((__half*)hU[0])[hidx] = __float2half(hreg0);
        ((__half*)hU[1])[hidx] = __float2half(hreg1);
    }
    pxs[0][t] = ldpx(0, t);
    if(t < 256) pxs[0][t+512] = ldpx(0, t+512);
    __syncthreads();

    const uint_t* h0p = hU[0]  + kh*68;
    const uint_t* h1p = hU[1]  + kh*68;
    const uint_t* r0p = rhU[0] + kh*68;
    const uint_t* r1p = rhU[1] + kh*68;

    for(int s=0; s<Tc; ++s){
        const int cur = s & 1;
        uint_t nf0 = 0, nf1 = 0;
        if(s < Tc-1){ nf0 = ldpx(s+1, t); if(t < 256) nf1 = ldpx(s+1, t+512); }

        const __half* pxcur = (const __half*)pxs[cur];
        float az0=0.f, az1=0.f, ar0=0.f, ar1=0.f;
        #pragma unroll
        for(int q=0;q<64;q+=4){
            uint4 hv0 = *(const uint4*)(h0p + q);
            uint4 hv1 = *(const uint4*)(h1p + q);
            az0=d2(wz[q+0],hv0.x,az0); ar0=d2(wr[q+0],hv0.x,ar0); az1=d2(wz[q+0],hv1.x,az1); ar1=d2(wr[q+0],hv1.x,ar1);
            az0=d2(wz[q+1],hv0.y,az0); ar0=d2(wr[q+1],hv0.y,ar0); az1=d2(wz[q+1],hv1.y,az1); ar1=d2(wr[q+1],hv1.y,ar1);
            az0=d2(wz[q+2],hv0.z,az0); ar0=d2(wr[q+2],hv0.z,ar0); az1=d2(wz[q+2],hv1.z,az1); ar1=d2(wr[q+2],hv1.z,ar1);
            az0=d2(wz[q+3],hv0.w,az0); ar0=d2(wr[q+3],hv0.w,ar0); az1=d2(wz[q+3],hv1.w,az1); ar1=d2(wr[q+3],hv1.w,ar1);
        }
        az0 += __shfl_xor(az0,1); az1 += __shfl_xor(az1,1);
        ar0 += __shfl_xor(ar0,1); ar1 += __shfl_xor(ar1,1);
        float z0 = sigmoidf_(__half2float(pxcur[        j]) + az0);
        float z1 = sigmoidf_(__half2float(pxcur[768   + j]) + az1);
        float r0 = sigmoidf_(__half2float(pxcur[256   + j]) + ar0);
        float r1 = sigmoidf_(__half2float(pxcur[768+256+j]) + ar1);
        if(kh==0){
            ((__half*)rhU[0])[hidx] = __float2half(r0*hreg0);
            ((__half*)rhU[1])[hidx] = __float2half(r1*hreg1);
        }
        __syncthreads();
        float ah0=0.f, ah1=0.f;
        #pragma unroll
        for(int q=0;q<64;q+=4){
            uint4 rv0 = *(const uint4*)(r0p + q);
            uint4 rv1 = *(const uint4*)(r1p + q);
            ah0=d2(wh[q+0],rv0.x,ah0); ah1=d2(wh[q+0],rv1.x,ah1);
            ah0=d2(wh[q+1],rv0.y,ah0); ah1=d2(wh[q+1],rv1.y,ah1);
            ah0=d2(wh[q+2],rv0.z,ah0); ah1=d2(wh[q+2],rv1.z,ah1);
            ah0=d2(wh[q+3],rv0.w,ah0); ah1=d2(wh[q+3],rv1.w,ah1);
        }
        ah0 += __shfl_xor(ah0,1); ah1 += __shfl_xor(ah1,1);
        float ht0 = tanhf_(__half2float(pxcur[512    + j]) + ah0);
        float ht1 = tanhf_(__half2float(pxcur[768+512+j]) + ah1);
        hreg0 = (1.f - z0)*hreg0 + z0*ht0;
        hreg1 = (1.f - z1)*hreg1 + z1*ht1;
        if(kh==0){
            ((__half*)hU[0])[hidx] = __float2half(hreg0);
            ((__half*)hU[1])[hidx] = __float2half(hreg1);
        }
        if(s < Tc-1){
            pxs[cur^1][t] = nf0;
            if(t < 256) pxs[cur^1][t+512] = nf1;
        }
        __syncthreads();
    }
    if(kh==0){
        hstate[(b0+0)*HH + j] = hreg0;
        hstate[(b0+1)*HH + j] = hreg1;
    }
}

// ---- LayerNorm + output projection ----
__global__ __launch_bounds__(256) void k_lnout(const float* __restrict__ hbuf,
    const float* __restrict__ lng, const float* __restrict__ lnb,
    const float* __restrict__ Wo, const float* __restrict__ bo,
    float* __restrict__ out){
    __shared__ __align__(16) float ln_s[HH];
    __shared__ float red[8];
    const int b = blockIdx.x, j = threadIdx.x;
    const float v = hbuf[(long)b*HH + j];
    float s = v, ss = v*v;
    const int lane = j & 63, w = j >> 6;
    for(int off=32; off>0; off>>=1){
        s  += __shfl_down(s,  off);
        ss += __shfl_down(ss, off);
    }
    if(lane == 0){ red[w] = s; red[4+w] = ss; }
    __syncthreads();
    float tot  = red[0]+red[1]+red[2]+red[3];
    float tot2 = red[4]+red[5]+red[6]+red[7];
    float mu  = tot  * (1.0f/HH);
    float var = tot2 * (1.0f/HH) - mu*mu;
    float rstd = rsqrtf(var + 1e-5f);
    ln_s[j] = (v - mu)*rstd*lng[j] + lnb[j];
    __syncthreads();
    if(j < OO){
        float acc = bo[j];
        const float4* w4 = (const float4*)(Wo + j*HH);
        const float4* l4 = (const float4*)ln_s;
        for(int k4=0;k4<HH/4;++k4){
            float4 wv = w4[k4], c = l4[k4];
            acc += wv.x*c.x + wv.y*c.y + wv.z*c.z + wv.w*c.w;
        }
        out[(long)b*OO + j] = acc;
    }
}

// ================= fallback path (round-0, proven, ~68MB ws) =================

__global__ __launch_bounds__(128) void k_emb_o(const float* __restrict__ x,
                                               const float* __restrict__ W,
                                               const float* __restrict__ bias,
                                               float* __restrict__ x1){
    __shared__ __align__(16) float xs[8][DD];
    const int j = threadIdx.x;
    const long row0 = (long)blockIdx.x * 32;
    const float bj = bias[j];
    const float4* W4 = (const float4*)(W + j*DD);
    for(int g=0; g<4; ++g){
        const long rbase = row0 + g*8;
        for(int r=0;r<8;++r) xs[r][j] = x[(rbase+r)*DD + j];
        __syncthreads();
        float acc[8];
        #pragma unroll
        for(int r=0;r<8;++r) acc[r] = bj;
        for(int k4=0;k4<DD/4;++k4){
            float4 w = W4[k4];
            #pragma unroll
            for(int r=0;r<8;++r){
                float4 c = ((const float4*)xs[r])[k4];
                acc[r] += c.x*w.x + c.y*w.y + c.z*w.z + c.w*w.w;
            }
        }
        for(int r=0;r<8;++r) x1[(rbase+r)*DD + j] = acc[r];
        __syncthreads();
    }
}

__global__ __launch_bounds__(128) void k_mean_o(const float* __restrict__ x1,
                                                float* __restrict__ xmean){
    const int j = threadIdx.x;
    const int b = blockIdx.x;
    const float* p = x1 + (long)b*TT*DD + j;
    float s = 0.f;
    for(int t=0;t<TT;++t) s += p[(long)t*DD];
    xmean[b*DD + j] = s * (1.0f/TT);
}

__global__ __launch_bounds__(128) void k_gate_o(float* __restrict__ xf,
    const float* __restrict__ xmask, const float* __restrict__ xdelta,
    const float* __restrict__ noise,
    const float* __restrict__ Wd1, const float* __restrict__ bd1,
    const float* __restrict__ Wd2, const float* __restrict__ bd2,
    const float* __restrict__ Wc,  const float* __restrict__ bc,
    const float* __restrict__ xmean){
    __shared__ __align__(16) float ds[8][DD];
    __shared__ __align__(16) float t1s[8][DD];
    __shared__ __align__(16) float xhs[8][DD];
    const int j = threadIdx.x;
    const long row0 = (long)blockIdx.x * 32;
    const int b = (int)(row0 >> 8);
    const float xm = xmean[b*DD + j];
    const float b1 = bd1[j], b2 = bd2[j], bcj = bc[j];
    const float4* Wd1_4 = (const float4*)(Wd1 + j*DD);
    const float4* Wd2_4 = (const float4*)(Wd2 + j*DD);
    const float4* Wc_4  = (const float4*)(Wc  + j*2*DD);
    for(int g=0; g<4; ++g){
        const long rbase = row0 + g*8;
        for(int r=0;r<8;++r)
            ds[r][j] = fminf(fmaxf(xdelta[(rbase+r)*DD + j], 0.f), 100.f);
        __syncthreads();
        float acc[8];
        #pragma unroll
        for(int r=0;r<8;++r) acc[r] = b1;
        for(int k4=0;k4<DD/4;++k4){
            float4 w = Wd1_4[k4];
            #pragma unroll
            for(int r=0;r<8;++r){
                float4 c = ((const float4*)ds[r])[k4];
                acc[r] += c.x*w.x + c.y*w.y + c.z*w.z + c.w*w.w;
            }
        }
        for(int r=0;r<8;++r) t1s[r][j] = fmaxf(acc[r], 0.f);
        __syncthreads();
        #pragma unroll
        for(int r=0;r<8;++r) acc[r] = b2;
        for(int k4=0;k4<DD/4;++k4){
            float4 w = Wd2_4[k4];
            #pragma unroll
            for(int r=0;r<8;++r){
                float4 c = ((const float4*)t1s[r])[k4];
                acc[r] += c.x*w.x + c.y*w.y + c.z*w.z + c.w*w.w;
            }
        }
        for(int r=0;r<8;++r){
            float gmm = sigmoidf_(acc[r]);
            float m  = xmask[(rbase+r)*DD + j];
            float xv = xf[(rbase+r)*DD + j];
            xhs[r][j] = m*xv + (1.f-m)*gmm*xm;
        }
        __syncthreads();
        #pragma unroll
        for(int r=0;r<8;++r) acc[r] = bcj;
        for(int k4=0;k4<DD/4;++k4){
            float4 w = Wc_4[k4];
            #pragma unroll
            for(int r=0;r<8;++r){
                float4 c = ((const float4*)xhs[r])[k4];
                acc[r] += c.x*w.x + c.y*w.y + c.z*w.z + c.w*w.w;
            }
        }
        for(int k4=0;k4<DD/4;++k4){
            float4 w = Wc_4[DD/4 + k4];
            #pragma unroll
            for(int r=0;r<8;++r){
                float4 c = ((const float4*)ds[r])[k4];
                acc[r] += c.x*w.x + c.y*w.y + c.z*w.z + c.w*w.w;
            }
        }
        for(int r=0;r<8;++r){
            float conf = sigmoidf_(acc[r]);
            float xh = xhs[r][j];
            float nz = noise[(rbase+r)*DD + j];
            xf[(rbase+r)*DD + j] = xh*conf + nz*(1.f-conf);
        }
        __syncthreads();
    }
}

__global__ __launch_bounds__(1024) void k_gru_o(const float* __restrict__ xf,
    const float* __restrict__ xmask, const float* __restrict__ xdelta,
    const float* __restrict__ Wz, const float* __restrict__ bz,
    const float* __restrict__ Wr, const float* __restrict__ br,
    const float* __restrict__ Wh, const float* __restrict__ bh,
    float* __restrict__ hout){
    __shared__ __align__(16) float xcs[4][KH];
    __shared__ __align__(16) float rh[4][HH];
    const int tid = threadIdx.x;
    const int j  = tid & 255;
    const int bl = tid >> 8;
    const long bbase = (long)blockIdx.x * 4;
    xcs[bl][384 + j] = 0.f;
    const float bzj = bz[j], brj = br[j], bhj = bh[j];
    const float4* Wz4 = (const float4*)(Wz + (long)j*KH);
    const float4* Wr4 = (const float4*)(Wr + (long)j*KH);
    const float4* Wh4 = (const float4*)(Wh + (long)j*KH);
    __syncthreads();
    for(int t=0;t<TT;++t){
        if(tid < 4*DD){
            int sb = tid >> 7, k = tid & 127;
            long row = (bbase + sb)*TT + t;
            xcs[sb][k]       = xf[row*DD + k];
            xcs[sb][128 + k] = xmask[row*DD + k];
            xcs[sb][256 + k] = fminf(fmaxf(xdelta[row*DD + k], 0.f), 100.f);
        }
        __syncthreads();
        const float4* cb = (const float4*)xcs[bl];
        float az = bzj, ar = brj;
        for(int k4=0;k4<KH/4;++k4){
            float4 wz = Wz4[k4], wrr = Wr4[k4];
            float4 v = cb[k4];
            az += v.x*wz.x + v.y*wz.y + v.z*wz.z + v.w*wz.w;
            ar += v.x*wrr.x + v.y*wrr.y + v.z*wrr.z + v.w*wrr.w;
        }
        float z = sigmoidf_(az);
        float r = sigmoidf_(ar);
        rh[bl][j] = r * xcs[bl][384 + j];
        __syncthreads();
        float ah = bhj;
        for(int k4=0;k4<96;++k4){
            float4 wh = Wh4[k4];
            float4 v = cb[k4];
            ah += v.x*wh.x + v.y*wh.y + v.z*wh.z + v.w*wh.w;
        }
        const float4* rp = (const float4*)rh[bl];
        for(int k4=0;k4<64;++k4){
            float4 wh = Wh4[96 + k4];
            float4 v = rp[k4];
            ah += v.x*wh.x + v.y*wh.y + v.z*wh.z + v.w*wh.w;
        }
        float ht = tanhf(ah);
        float hold = xcs[bl][384 + j];
        float hn = (1.f - z)*hold + z*ht;
        xcs[bl][384 + j] = hn;
        __syncthreads();
    }
    hout[(bbase + bl)*HH + j] = xcs[bl][384 + j];
}

// ================= launch =================

extern "C" void kernel_launch(void* const* d_in, const int* in_sizes, int n_in,
                              void* d_out, int out_size, void* d_ws, size_t ws_size,
                              hipStream_t stream){
    const float* x      = (const float*)d_in[0];
    const float* xmask  = (const float*)d_in[1];
    const float* xdelta = (const float*)d_in[2];
    const float* noise  = (const float*)d_in[3];
    const float* W_emb  = (const float*)d_in[4];
    const float* b_emb  = (const float*)d_in[5];
    const float* W_d1   = (const float*)d_in[6];
    const float* b_d1   = (const float*)d_in[7];
    const float* W_d2   = (const float*)d_in[8];
    const float* b_d2   = (const float*)d_in[9];
    const float* W_c    = (const float*)d_in[10];
    const float* b_c    = (const float*)d_in[11];
    const float* W_z    = (const float*)d_in[12];
    const float* b_z    = (const float*)d_in[13];
    const float* W_r    = (const float*)d_in[14];
    const float* b_r    = (const float*)d_in[15];
    const float* W_h    = (const float*)d_in[16];
    const float* b_h    = (const float*)d_in[17];
    const float* ln_g   = (const float*)d_in[18];
    const float* ln_b   = (const float*)d_in[19];
    const float* W_o    = (const float*)d_in[20];
    const float* b_o    = (const float*)d_in[21];
    float* out = (float*)d_out;
    char* ws = (char*)d_ws;

    int Tc = 0, lTc = 0;
    {
        const int cand[3]  = {128, 64, 32};
        const int lcand[3] = {7, 6, 5};
        for(int i=0;i<3;++i){
            size_t need = SZ_XC + (size_t)cand[i]*786432 + TAIL_SZ;
            if(ws_size >= need){ Tc = cand[i]; lTc = lcand[i]; break; }
        }
    }

    if(Tc > 0){
        __half* xc    = (__half*)(ws);
        char*   p     = ws + SZ_XC;
        __half* pxc   = (__half*)p;              p += (size_t)Tc*786432;
        __half* Wcat  = (__half*)p;              p += 589824;
        __half* Wrec  = (__half*)p;              p += 393216;
        float*  bcat  = (float*)p;               p += 3072;
        float*  xmean = (float*)p;               p += 262144;
        float*  hstate= (float*)p;               p += 524288;
        __half* Wembh = (__half*)p;              p += 32768;
        __half* Wd1h  = (__half*)p;              p += 32768;
        __half* Wd2h  = (__half*)p;              p += 32768;
        __half* Wch   = (__half*)p;

        k_wprep<<<dim3(768),   dim3(128), 0, stream>>>(W_z,W_r,W_h,b_z,b_r,b_h, Wcat, Wrec, bcat);
        k_cvt  <<<dim3(128),   dim3(256), 0, stream>>>(W_emb, W_d1, W_d2, W_c, Wembh, Wd1h, Wd2h, Wch);
        k_meanx<<<dim3(BB),    dim3(256), 0, stream>>>(x, W_emb, b_emb, xmean);
        k_embgate<<<dim3(BT/128), dim3(256), 0, stream>>>(x, xmask, xdelta, noise,
                                                          Wembh, b_emb, Wd1h, b_d1,
                                                          Wd2h, b_d2, Wch, b_c, xmean, xc);
        const int nchunk = TT / Tc;
        for(int c=0; c<nchunk; ++c){
            k_projm<<<dim3(BB*Tc/128, 6), dim3(256), 0, stream>>>(xc, Wcat, bcat, pxc, lTc, c);
            k_gruc <<<dim3(BB/2), dim3(512), 0, stream>>>(pxc, Wrec, hstate, Tc, c==0 ? 1 : 0);
        }
        k_lnout<<<dim3(BB), dim3(256), 0, stream>>>(hstate, ln_g, ln_b, W_o, b_o, out);
    } else {
        float* xf    = (float*)ws;
        float* xmean = (float*)(ws + (size_t)BT*DD*4);
        float* hbuf  = (float*)(ws + (size_t)BT*DD*4 + (size_t)BB*DD*4);
        k_emb_o  <<<dim3(BT/32), dim3(128), 0, stream>>>(x, W_emb, b_emb, xf);
        k_mean_o <<<dim3(BB),    dim3(128), 0, stream>>>(xf, xmean);
        k_gate_o <<<dim3(BT/32), dim3(128), 0, stream>>>(xf, xmask, xdelta, noise,
                                                         W_d1,b_d1,W_d2,b_d2,W_c,b_c, xmean);
        k_gru_o  <<<dim3(BB/4),  dim3(1024),0, stream>>>(xf, xmask, xdelta,
                                                         W_z,b_z,W_r,b_r,W_h,b_h, hbuf);
        k_lnout  <<<dim3(BB),    dim3(256), 0, stream>>>(hbuf, ln_g, ln_b, W_o, b_o, out);
    }
}